// Round 11
// baseline (214.808 us; speedup 1.0000x reference)
//
#include <hip/hip_runtime.h>

// SSIM loss via separable 11-tap Gaussian — R20: R19's verified compute in
// PERSISTENT PIPELINED blocks (the discriminating experiment for the ~50us
// floor). Evidence: R15/R16/R17/R19 — four structurally different kernels
// (coop hq, 8-wave, pair-pipelined, indep-wave MFMA) ALL pin at 49-51us
// with no pipe >40%; VALU-issue budget ~18us, MFMA ~6us, HBM ~8us -> ~30us
// of stall common to all short-block structures: every ~1us block start
// exposes phase-A global latency, and co-resident blocks batch-start so no
// wave can fill the hole. R20 keeps compute/staging IDENTICAL to R19 and
// only changes lifetime: 1536 blocks (6/CU) x 8 tiles, LDS double-buffer,
// per-iter pipeline {issue loads(i+1) -> compute(i) from buf[cur] ->
// stage(i+1) into buf[cur^1] -> ldsBarrier}. One barrier/iter (double
// buffer makes it sufficient); latency hides under ~2000cyc compute x8.
// Pre-committed readings: ~32-38us => convoy theory confirmed; ~50us
// unchanged => memory-system wall at this traffic shape -> roofline call.
//  - Compute (R18/R19-verified): wave owns 16x16 out tile (wr=wv>>1,
//    wc=wv&1); A-op = 4x ds_read_b128 rows 16wr+16b+lm, word col 8wc+4lg;
//    horizontal mfma_16x16x32 (taps bt[e]=g[8lg+e-lm-3]); B-phase D-layout
//    == K=16 B-op fragment -> vertical = 2 chained mfma_16x16x16f16
//    (ca_b[e]=g[16b+4lg+e-lm-3]); 5 quantities {x,y,xx,yy,xy}.
//  - Staging (R19-verified): 48x48 window, float4 -> cvt_pk -> f16 LDS,
//    SXW=28 (every b128 16B-aligned, 2-way bank overlap = free).
//  - 8 tiles/block = horizontally adjacent (same 256x32 strip): halos
//    overlap -> L1/L2 hits; XCD-bijective swizzle on BLOCK id.
// Reduction history (do NOT re-fuse): R13 fences -> 9x; R14 same-line
// relaxed atomics -> 3x (XCD ping-pong). Two-kernel scheme stands.
// Numerics: f16 data/taps (center-corrected), f32 accum -> absmax 0.0039.

typedef __fp16 f16x8 __attribute__((ext_vector_type(8)));
typedef __fp16 f16x4 __attribute__((ext_vector_type(4)));
typedef float  f32x4 __attribute__((ext_vector_type(4)));
typedef unsigned u32x2 __attribute__((ext_vector_type(2)));
typedef unsigned u32x4 __attribute__((ext_vector_type(4)));

__device__ __forceinline__ unsigned pk2(float a, float b) {
    return __builtin_bit_cast(unsigned, __builtin_amdgcn_cvt_pkrtz(a, b));
}
__device__ __forceinline__ f32x4 mfmaB(f16x8 a, f16x8 b, f32x4 c) {
    return __builtin_amdgcn_mfma_f32_16x16x32_f16(a, b, c, 0, 0, 0);
}
__device__ __forceinline__ f32x4 mfmaC(f16x4 a, f16x4 b, f32x4 c) {
    return __builtin_amdgcn_mfma_f32_16x16x16f16(a, b, c, 0, 0, 0);
}
// LDS-only barrier: orders LDS across waves WITHOUT draining vmcnt.
__device__ __forceinline__ void ldsBarrier() {
    asm volatile("s_waitcnt lgkmcnt(0)\n\ts_barrier" ::: "memory");
}

#define SXW 28   // staged words/row; mult of 4 -> all b128 reads 16B-aligned
#define TPB 8    // tiles per block

__global__ __launch_bounds__(256, 6) void ssim_main(
    const float* __restrict__ xg, const float* __restrict__ yg,
    const float* __restrict__ w2d, float* __restrict__ part)
{
    __shared__ __align__(16) unsigned sx[2][48 * SXW];  // 2 x 5376 B
    __shared__ __align__(16) unsigned sy[2][48 * SXW];  // 2 x 5376 B
    __shared__ unsigned tbp[64];
    __shared__ float gsf[11];
    __shared__ float wred[4];

    const int tid = threadIdx.x;
    const int nblk = (int)gridDim.x;            // 1536 (Z*32), %8 == 0
    const int bid = (int)blockIdx.x;
    const int swzb = (bid & 7) * (nblk >> 3) + (bid >> 3);
    const int tbase = swzb * TPB;               // 8 x-adjacent tiles

    // ---- Per-tile helpers (R19-verified addressing) ----
    float4 lx0, ly0, lx1, ly1, lx2, ly2;        // prefetch registers
    const bool h2 = tid < 64;
    auto ldtile = [&](int i) {
        const int t = tbase + i;
        const int tz = t >> 8, ty = (t >> 4) & 15, tx = t & 15;
        const int X0 = 32 * tx - 8, Y0 = 32 * ty - 8;
        const bool inter = (tx > 0) & (tx < 15) & (ty > 0) & (ty < 15);
        const float* __restrict__ xp = xg + (size_t)tz * (512 * 512);
        const float* __restrict__ yp = yg + (size_t)tz * (512 * 512);
        auto ldit = [&](int it, float4& vx, float4& vy) {
            const int r = it / 12, c4 = it - r * 12;
            const int gr = Y0 + r, gc0 = X0 + 4 * c4;
            if (inter) {                          // block-uniform branch
                const int o = gr * 512 + gc0;
                vx = *(const float4*)&xp[o];
                vy = *(const float4*)&yp[o];
            } else {
                const bool rok = (unsigned)gr < 512u;
                float tx4[4], ty4[4];
                #pragma unroll
                for (int j = 0; j < 4; ++j) {
                    const int gc = gc0 + j;
                    const bool ok = rok & ((unsigned)gc < 512u);
                    const int o = ok ? (gr * 512 + gc) : 0;
                    tx4[j] = ok ? xp[o] : 0.f;
                    ty4[j] = ok ? yp[o] : 0.f;
                }
                vx = make_float4(tx4[0], tx4[1], tx4[2], tx4[3]);
                vy = make_float4(ty4[0], ty4[1], ty4[2], ty4[3]);
            }
        };
        ldit(tid, lx0, ly0);
        ldit(tid + 256, lx1, ly1);
        if (h2) ldit(tid + 512, lx2, ly2);
    };
    auto stage = [&](int buf) {
        auto wrt = [&](int it, const float4& vx, const float4& vy) {
            const int r = it / 12, c4 = it - r * 12;
            *(uint2*)&sx[buf][r * SXW + 2 * c4] =
                make_uint2(pk2(vx.x, vx.y), pk2(vx.z, vx.w));
            *(uint2*)&sy[buf][r * SXW + 2 * c4] =
                make_uint2(pk2(vy.x, vy.y), pk2(vy.z, vy.w));
        };
        wrt(tid, lx0, ly0);
        wrt(tid + 256, lx1, ly1);
        if (h2) wrt(tid + 512, lx2, ly2);
    };

    // Tap table, built ENTIRELY by wave 0 (intra-wave LDS ordering).
    // 1D kernel = row sums of outer(g,g); f16 taps with center correction;
    // tbp[i] = (tap(i-19), tap(i-18)) packed f16x2.
    if (tid < 11) {
        float s = 0.0f;
        #pragma unroll
        for (int j = 0; j < 11; ++j) s += w2d[tid * 11 + j];
        gsf[tid] = s;
    }
    if (tid < 64) {
        float ssum = 0.0f;
        #pragma unroll
        for (int k = 0; k < 11; ++k)
            if (k != 5) ssum += (float)(__fp16)gsf[k];
        const __fp16 cc = (__fp16)(1.0f - ssum);
        auto tap = [&](int t) -> __fp16 {
            if ((unsigned)t > 10u) return (__fp16)0.f;
            return (t == 5) ? cc : (__fp16)gsf[t];
        };
        const int t = tid - 19;
        const unsigned short lo = __builtin_bit_cast(unsigned short, tap(t));
        const unsigned short hi = __builtin_bit_cast(unsigned short, tap(t + 1));
        tbp[tid] = (unsigned)lo | ((unsigned)hi << 16);
    }

    // Prologue: tile 0 staged into buf 0.
    ldtile(0);
    stage(0);
    ldsBarrier();                               // staging + tbp visible

    const int lane = tid & 63, wv = tid >> 6;
    const int lm = lane & 15, lg = lane >> 4;
    const int wr = wv >> 1, wc = wv & 1;

    // Tap fragments (verified): B bt[e]=g[8lg+e-lm-3]; C ca_b[e]=
    // g[16b+4lg+e-lm-3]. Pair indices in [1,46].
    f16x8 bt;
    f16x4 ca0, ca1;
    {
        const int ib = 8 * lg - lm + 16;
        const u32x4 wb = {tbp[ib], tbp[ib + 2], tbp[ib + 4], tbp[ib + 6]};
        bt = __builtin_bit_cast(f16x8, wb);
        const int ic = 4 * lg - lm + 16;
        const u32x2 w0 = {tbp[ic], tbp[ic + 2]};
        const u32x2 w1 = {tbp[ic + 16], tbp[ic + 18]};
        ca0 = __builtin_bit_cast(f16x4, w0);
        ca1 = __builtin_bit_cast(f16x4, w1);
    }

    const int rbase = (16 * wr + lm) * SXW + 8 * wc + 4 * lg;
    const f32x4 z4 = {0.f, 0.f, 0.f, 0.f};
    const float C1 = 1e-4f, C2 = 9e-4f;
    float lsum = 0.0f;

    // Main pipeline: loads(i+1) || compute(i) ; stage(i+1) ; barrier.
    for (int i = 0; i < TPB; ++i) {
        const int cur = i & 1;
        if (i + 1 < TPB) ldtile(i + 1);         // issue early, wait at stage

        const unsigned* __restrict__ sxc = sx[cur];
        const unsigned* __restrict__ syc = sy[cur];
        const f16x8 xd0 = __builtin_bit_cast(f16x8, *(const u32x4*)&sxc[rbase]);
        const f16x8 xd1 = __builtin_bit_cast(f16x8, *(const u32x4*)&sxc[rbase + 16 * SXW]);
        const f16x8 yd0 = __builtin_bit_cast(f16x8, *(const u32x4*)&syc[rbase]);
        const f16x8 yd1 = __builtin_bit_cast(f16x8, *(const u32x4*)&syc[rbase + 16 * SXW]);

        f32x4 acc[5];
        #pragma unroll
        for (int q = 0; q < 5; ++q) {
            f16x8 a0, a1;
            if (q == 0)      { a0 = xd0;       a1 = xd1; }
            else if (q == 1) { a0 = yd0;       a1 = yd1; }
            else if (q == 2) { a0 = xd0 * xd0; a1 = xd1 * xd1; }
            else if (q == 3) { a0 = yd0 * yd0; a1 = yd1 * yd1; }
            else             { a0 = xd0 * yd0; a1 = xd1 * yd1; }
            const f32x4 d0 = mfmaB(a0, bt, z4);
            const f32x4 d1 = mfmaB(a1, bt, z4);
            const u32x2 h0 = {pk2(d0[0], d0[1]), pk2(d0[2], d0[3])};
            const u32x2 h1 = {pk2(d1[0], d1[1]), pk2(d1[2], d1[3])};
            const f32x4 p0 = mfmaC(ca0, __builtin_bit_cast(f16x4, h0), z4);
            acc[q]         = mfmaC(ca1, __builtin_bit_cast(f16x4, h1), p0);
        }

        #pragma unroll
        for (int r = 0; r < 4; ++r) {
            const float mx = acc[0][r], my = acc[1][r];
            const float exx = acc[2][r], eyy = acc[3][r];
            const float exy = acc[4][r];
            const float mx2 = mx * mx, my2 = my * my, mxy = mx * my;
            const float vx = exx - mx2, vy = eyy - my2, vxy = exy - mxy;
            const float num = (2.0f * mxy + C1) * (2.0f * vxy + C2);
            const float den = (mx2 + my2 + C1) * (vx + vy + C2) + 1e-12f;
            lsum = fmaf(num, __builtin_amdgcn_rcpf(den), lsum);
        }

        if (i + 1 < TPB) stage(cur ^ 1);        // vmcnt waits fold in here
        ldsBarrier();                           // ends compute(cur)+stage(alt)
    }

    // Wave reduce -> 4-float LDS -> one plain store per block.
    #pragma unroll
    for (int off = 32; off > 0; off >>= 1)
        lsum += __shfl_down(lsum, off, 64);
    if ((tid & 63) == 0) wred[tid >> 6] = lsum;
    ldsBarrier();
    if (tid == 0)
        part[bid] = wred[0] + wred[1] + wred[2] + wred[3];
}

__global__ __launch_bounds__(1024) void ssim_reduce(
    const float* __restrict__ part, float* __restrict__ out,
    int n, float invN)
{
    __shared__ float wred[16];
    float s = 0.0f;
    for (int i = threadIdx.x; i < n; i += 1024) s += part[i];
    #pragma unroll
    for (int off = 32; off > 0; off >>= 1)
        s += __shfl_down(s, off, 64);
    if ((threadIdx.x & 63) == 0) wred[threadIdx.x >> 6] = s;
    __syncthreads();
    if (threadIdx.x == 0) {
        float tot = 0.0f;
        #pragma unroll
        for (int w = 0; w < 16; ++w) tot += wred[w];
        out[0] = 1.0f - tot * invN;
    }
}

extern "C" void kernel_launch(void* const* d_in, const int* in_sizes, int n_in,
                              void* d_out, int out_size, void* d_ws, size_t ws_size,
                              hipStream_t stream) {
    const float* x   = (const float*)d_in[0];
    const float* y   = (const float*)d_in[1];
    const float* w2d = (const float*)d_in[2];  // (3,1,11,11); channels identical
    float* out  = (float*)d_out;
    float* part = (float*)d_ws;                // 1536 floats = 6 KB

    const int H = 512, W = 512;
    const int total = in_sizes[0];              // 16*3*512*512
    const int Z = total / (H * W);              // 48

    // 48 images x 256 tiles(32x32) = 12288 tiles = 1536 blocks x 8 tiles.
    const int nblk = Z * 256 / TPB;
    ssim_main<<<dim3(nblk), 256, 0, stream>>>(x, y, w2d, part);

    const float invN = 1.0f / (float)total;
    ssim_reduce<<<1, 1024, 0, stream>>>(part, out, nblk, invN);
}